// Round 1
// 134424.133 us; speedup vs baseline: 1.0262x; 1.0262x over previous
//
#include <hip/hip_runtime.h>
#include <hip/hip_bf16.h>
#include <math.h>

// ============================================================================
// RNNDecoder v3: 256 persistent blocks (all CUs), 32 same-XCD blocks per
// group j-split BOTH the GRU and the cc layer with all weight slices
// LDS-resident in f32 (bit-identical values to v2's ws copies). Attention +
// logits/argmax stay per-row-owner (owner row = blk for blk<128) with
// verbatim v2 code so the argmax trajectory is unchanged. 4 group-local sync
// rounds per step. Loop-phase global reads are all L1/L2-resident.
// ============================================================================

typedef unsigned short u16;
typedef unsigned int u32;
typedef float f4 __attribute__((ext_vector_type(4)));

#define NB 256
#define NT 1024
#define Ln 500
#define Hn 512
#define LDn 256
#define UDn 128
#define Vn 33
#define Tn 500
#define SENT_V 0x9E3779B1u

// ---- workspace u32 offsets ----
#define W_FLG   0u          // [500][8][16] counters: [0]=h(32) [1]=cu(16) [2]=cc(32) [3]=tok(16)
#define W_INITC 64000u
#define W_SENT  64001u
#define W_GEM   64064u      // f32 [33][1536]   embed@W_ih^T + b_ih
#define W_M2T   114752u     // f32 [128u][512j] catW_right@memW, transposed
#define W_CB    180288u     // f32 [512]        cat_b + catWr@mem_b
#define W_OWT   180800u     // f32 [512][34]    out_W^T padded
#define W_OB    198208u     // f32 [64]
#define W_H     198272u     // f32 [2][128][512] h double buffer
#define W_TOK   329344u     // int [128]
#define W_CUV   329472u     // f32 [128][128]   scaled attention context
#define W_CCB   345856u     // f32 [128][512]   cc vectors
#define W_END   411392u

__device__ __forceinline__ float b2f(u16 v) {
  u32 x = ((u32)v) << 16; float f; __builtin_memcpy(&f, &x, 4); return f;
}
__device__ __forceinline__ float bitsf(u32 x) {
  float f; __builtin_memcpy(&f, &x, 4); return f;
}
__device__ __forceinline__ u16 f2b(float f) {  // RNE
  u32 x; __builtin_memcpy(&x, &f, 4);
  x += 0x7fffu + ((x >> 16) & 1u);
  return (u16)(x >> 16);
}
// mode==1: buffer holds bf16; mode==0: fp32
__device__ __forceinline__ float ldv(const void* p, int i, int mode) {
  return mode ? b2f(((const u16*)p)[i]) : ((const float*)p)[i];
}
__device__ __forceinline__ u32 aload(u32* p) {
  return __hip_atomic_load(p, __ATOMIC_ACQUIRE, __HIP_MEMORY_SCOPE_AGENT);
}
__device__ __forceinline__ void waitGe(u32* p, u32 tgt) {
  while (aload(p) < tgt) __builtin_amdgcn_s_sleep(4);
}
__device__ __forceinline__ void arrive(u32* p) {
  __hip_atomic_fetch_add(p, 1u, __ATOMIC_RELEASE, __HIP_MEMORY_SCOPE_AGENT);
}
__device__ __forceinline__ void astore(u32* p, u32 v) {
  __hip_atomic_store(p, v, __ATOMIC_RELEASE, __HIP_MEMORY_SCOPE_AGENT);
}

extern "C" __global__ void __launch_bounds__(1024)
rnn_v3(const void* latent, const void* ulat, const void* embd,
       const void* hidW, const void* hidb, const void* memW, const void* memb,
       const void* Wih, const void* Whh, const void* bih, const void* bhh,
       const void* catW, const void* catb, const void* outW, const void* outb,
       void* out, u32* ws) {
  // ---- LDS-persistent f32 weight slices (j-slice = m*16..m*16+16) ----
  // strides padded (516/132) so 16 jl rows spread across banks; 16B-aligned.
  __shared__ __align__(16) float Whh_l[3 * 16 * 516];  // 99072 B [g][jl][k]
  __shared__ __align__(16) float cWT_l[16 * 516];      // 33024 B [jl][k]
  __shared__ __align__(16) float M2T_l[16 * 132];      //  8448 B [jl][u]
  __shared__ float bhh_l[48];
  __shared__ float cb_l[16];
  __shared__ __align__(16) char arena[11520];          // phase-local scratch
  __shared__ u32 s_det;

  const int tid = threadIdx.x, blk = blockIdx.x;
  const int wv = tid >> 6, lane = tid & 63;
  const int gt = blk & 7;   // group id == XCD (blk%8)
  const int m  = blk >> 3;  // member 0..31; owner iff m<16 (owner row = blk)
  const int gtid = blk * NT + tid;

  // ---- dtype detection: embed row PAD=1 is zero iff bf16 ----
  if (tid == 0) s_det = 0u;
  __syncthreads();
  if (tid < 256) {
    u32 v = ((const u32*)embd)[256 + tid];
    if (v) atomicOr(&s_det, 1u);
  }
  __syncthreads();
  const int mode = (s_det == 0u) ? 1 : 0;

  float* GEM   = (float*)(ws + W_GEM);
  float* M2T   = (float*)(ws + W_M2T);
  float* cbF   = (float*)(ws + W_CB);
  float* oWT   = (float*)(ws + W_OWT);
  float* obF   = (float*)(ws + W_OB);
  float* hbuf  = (float*)(ws + W_H);
  int*   tokb  = (int*)(ws + W_TOK);
  float* cuvws = (float*)(ws + W_CUV);
  float* ccbF  = (float*)(ws + W_CCB);

  // ---- LDS slices sourced directly from kernel inputs (values identical to
  //      v2's ws f32 copies: ldv() is the same conversion) ----
  for (int i = tid; i < 24576; i += NT) {      // W_hh j-slice
    int k = i & 511, rem = i >> 9;             // rem = g*16+jl
    int g = rem >> 4, jl = rem & 15;
    Whh_l[rem * 516 + k] = ldv(Whh, (g * 512 + m * 16 + jl) * 512 + k, mode);
  }
  for (int i = tid; i < 8192; i += NT) {       // catW-left^T j-slice
    int jl = i & 15, k = i >> 4;
    cWT_l[jl * 516 + k] = ldv(catW, (m * 16 + jl) * 1024 + k, mode);
  }
  if (tid < 48) bhh_l[tid] = ldv(bhh, (tid >> 4) * 512 + m * 16 + (tid & 15), mode);

  // ======================= one-time ws init =================================
  for (int i = gtid; i < 64000; i += NB * NT) ws[W_FLG + i] = 0u;       // flags
  for (int i = gtid; i < 131072; i += NB * NT) ws[W_H + i] = 0u;        // h zero
  if (gtid < 128) tokb[gtid] = 0;                                       // SOS
  for (int i = gtid; i < 17408; i += NB * NT) {        // out_W^T [512][34]
    int j = i / 34, v = i - j * 34;
    oWT[i] = (v < Vn) ? ldv(outW, v * Hn + j, mode) : 0.f;
  }
  if (gtid < 64) obF[gtid] = (gtid < Vn) ? ldv(outb, gtid, mode) : 0.f;
  if (gtid < 50688) {                                  // GEM = embed@Wih^T+bih
    int v = gtid / 1536, j = gtid - v * 1536;
    float a = ldv(bih, j, mode);
    for (int k = 0; k < Hn; k++)
      a += ldv(embd, v * Hn + k, mode) * ldv(Wih, j * Hn + k, mode);
    GEM[gtid] = a;
  }
  if (gtid < 65536) {                                  // M2^T[u][j]
    int u = gtid >> 9, j = gtid & 511;
    float a = 0.f;
    for (int h = 0; h < Hn; h++)
      a += ldv(catW, j * 1024 + 512 + h, mode) * ldv(memW, h * UDn + u, mode);
    M2T[gtid] = a;
  }
  if (gtid < 512) {                                    // cbias
    int j = gtid;
    float a = ldv(catb, j, mode);
    for (int h = 0; h < Hn; h++)
      a += ldv(catW, j * 1024 + 512 + h, mode) * ldv(memb, h, mode);
    cbF[j] = a;
  }
  if (gtid < 65536) {                                  // h0 -> parity 0
    int b = gtid >> 9, k = gtid & 511;
    float a = ldv(hidb, k, mode);
    for (int q = 0; q < LDn; q++)
      a += ldv(latent, b * LDn + q, mode) * ldv(hidW, k * LDn + q, mode);
    hbuf[b * Hn + k] = a;
  }
  __threadfence();
  __syncthreads();
  if (tid == 0) {  // poison-agnostic device barrier
    if (blk == 0) {
      __hip_atomic_store(ws + W_INITC, 0u, __ATOMIC_RELAXED, __HIP_MEMORY_SCOPE_AGENT);
      astore(ws + W_SENT, SENT_V);
    }
    while (aload(ws + W_SENT) != SENT_V) __builtin_amdgcn_s_sleep(8);
    arrive(ws + W_INITC);
    waitGe(ws + W_INITC, NB);
  }
  __syncthreads();
  // ws-derived LDS slices (need init barrier first)
  for (int i = tid; i < 2048; i += NT) {       // M2^T j-slice
    int jl = i & 15, u = i >> 4;
    M2T_l[jl * 132 + u] = M2T[u * 512 + m * 16 + jl];
  }
  if (tid < 16) cb_l[tid] = cbF[m * 16 + tid];
  __syncthreads();

  // ---- phase-local arena views (phases are barrier-separated) ----
  float* gh3   = (float*)arena;            // GRU: [3][16r][16jl]      3072 B
  float* hown  = (float*)arena;            // owner: [512]             2048 B
  float* Bpart = (float*)(arena + 2048);   // owner: [8][128]          4096 B
  float* ps    = (float*)(arena + 6144);   // owner: [128]
  float* ss    = (float*)(arena + 6656);   // owner: [512]
  float* es    = (float*)(arena + 8704);   // owner: [512]
  float* misc  = (float*)(arena + 10752);  // owner: [16]
  float* ccp2  = (float*)arena;            // cc: [16r][16jl][2]       2048 B
  float* ccs   = (float*)arena;            // logits: [512]
  float* lgs   = (float*)(arena + 2048);   // logits: [16*34]

  // ======================= 500 decode steps =================================
  for (int t = 0; t < Tn; t++) {
    u32* flg = ws + W_FLG + (unsigned)(t * 8 + gt) * 16u;
    const float* hc = hbuf + (t & 1) * 65536;
    float* hnw = hbuf + ((t & 1) ^ 1) * 65536;

    if (t > 0) {  // prev step tokens (implies prev h/cc all complete)
      if (wv == 0) waitGe(ws + W_FLG + (unsigned)((t - 1) * 8 + gt) * 16u + 3, 16u);
      __syncthreads();
    }

    // ---- GRU: member computes its 16-j slice for all 16 group rows --------
    // exact v2 order: 8 chunks of 64 k, descending fma nest per quad,
    // chunk partials summed in order, then +bhh.
    if (tid < 192) {
      const int g = tid / 64, rem = tid & 63, rq = rem >> 4, jl = rem & 15;
      const float* wbase = Whh_l + (g * 16 + jl) * 516;
      const float* h0p = hc + ((rq * 4 + 0) * 8 + gt) * Hn;
      const float* h1p = hc + ((rq * 4 + 1) * 8 + gt) * Hn;
      const float* h2p = hc + ((rq * 4 + 2) * 8 + gt) * Hn;
      const float* h3p = hc + ((rq * 4 + 3) * 8 + gt) * Hn;
      float s0 = 0.f, s1 = 0.f, s2 = 0.f, s3 = 0.f;
      for (int c = 0; c < 8; c++) {
        float a0 = 0.f, a1 = 0.f, a2 = 0.f, a3 = 0.f;
#pragma unroll
        for (int k4 = 0; k4 < 16; k4++) {
          const f4 w = *(const f4*)(wbase + c * 64 + k4 * 4);
          f4 x;
          x = *(const f4*)(h0p + c * 64 + k4 * 4);
          a0 = fmaf(w.x, x.x, fmaf(w.y, x.y, fmaf(w.z, x.z, fmaf(w.w, x.w, a0))));
          x = *(const f4*)(h1p + c * 64 + k4 * 4);
          a1 = fmaf(w.x, x.x, fmaf(w.y, x.y, fmaf(w.z, x.z, fmaf(w.w, x.w, a1))));
          x = *(const f4*)(h2p + c * 64 + k4 * 4);
          a2 = fmaf(w.x, x.x, fmaf(w.y, x.y, fmaf(w.z, x.z, fmaf(w.w, x.w, a2))));
          x = *(const f4*)(h3p + c * 64 + k4 * 4);
          a3 = fmaf(w.x, x.x, fmaf(w.y, x.y, fmaf(w.z, x.z, fmaf(w.w, x.w, a3))));
        }
        s0 += a0; s1 += a1; s2 += a2; s3 += a3;
      }
      const float bb = bhh_l[g * 16 + jl];
      gh3[(g * 16 + rq * 4 + 0) * 16 + jl] = s0 + bb;
      gh3[(g * 16 + rq * 4 + 1) * 16 + jl] = s1 + bb;
      gh3[(g * 16 + rq * 4 + 2) * 16 + jl] = s2 + bb;
      gh3[(g * 16 + rq * 4 + 3) * 16 + jl] = s3 + bb;
    }
    __syncthreads();
    if (tid < 256) {  // gate nonlinearity + h update (verbatim v2 formulas)
      const int r = tid >> 4, jl = tid & 15;
      const int jglob = m * 16 + jl;
      const int bg = r * 8 + gt;
      int tk = tokb[bg];
      if ((unsigned)tk > 32u) tk = 0;  // defensive clamp
      const float giR = GEM[tk * 1536 + jglob];
      const float giZ = GEM[tk * 1536 + 512 + jglob];
      const float giN = GEM[tk * 1536 + 1024 + jglob];
      const float rr = 1.f / (1.f + expf(-(giR + gh3[(0 + r) * 16 + jl])));
      const float zz = 1.f / (1.f + expf(-(giZ + gh3[(16 + r) * 16 + jl])));
      const float nn = tanhf(giN + rr * gh3[(32 + r) * 16 + jl]);
      const float hv = hc[bg * Hn + jglob];
      hnw[bg * Hn + jglob] = (1.f - zz) * nn + zz * hv;
    }
    __syncthreads();
    if (tid == 0) { __threadfence(); arrive(flg + 0); }

    // ---- owner attention (verbatim v2; owner row = blk) -------------------
    if (m < 16) {
      if (wv == 0) waitGe(flg + 0, 32u);
      __syncthreads();
      if (tid < Hn) hown[tid] = hnw[blk * Hn + tid];
      __syncthreads();
      {  // p = memW^T h_new
        const int u = tid & 127, c8 = tid >> 7;
        float a = 0.f;
        for (int k = c8 * 64; k < c8 * 64 + 64; k++)
          a = fmaf(ldv(memW, k * UDn + u, mode), hown[k], a);
        Bpart[c8 * UDn + u] = a;
      }
      __syncthreads();
      if (tid < 128) {
        float s = 0.f;
#pragma unroll
        for (int c = 0; c < 8; c++) s += Bpart[c * UDn + tid];
        ps[tid] = s;
      } else if (tid < 192) {  // s0 = h_new . mem_b
        const int ln = tid - 128;
        float a = 0.f;
#pragma unroll
        for (int i = 0; i < 8; i++) { int k = ln + i * 64; a = fmaf(hown[k], ldv(memb, k, mode), a); }
        for (int o = 32; o; o >>= 1) a += __shfl_down(a, o);
        if (ln == 0) misc[0] = a;
      }
      __syncthreads();
      {  // scores[l] = p . ul[blk][l] + s0
        const int l = (wv << 5) + (lane >> 1), uh = lane & 1;
        float val = 0.f;
        if (l < Ln) {
          if (mode) {
            const u32* q = (const u32*)ulat + ((size_t)blk * Ln + l) * 64 + uh * 32;
            for (int i = 0; i < 32; i++) {
              const u32 d = q[i];
              val = fmaf(bitsf(d << 16), ps[uh * 64 + i * 2], val);
              val = fmaf(bitsf(d & 0xffff0000u), ps[uh * 64 + i * 2 + 1], val);
            }
          } else {
            const float* q = (const float*)ulat + ((size_t)blk * Ln + l) * UDn + uh * 64;
            for (int i = 0; i < 64; i++) val = fmaf(q[i], ps[uh * 64 + i], val);
          }
        }
        const float v2 = __shfl_down(val, 1);
        if ((lane & 1) == 0 && l < Ln) ss[l] = val + v2 + misc[0];
      }
      __syncthreads();
      if (wv == 0) {  // softmax stats over 500
        float mx = -3.4e38f;
        for (int i = 0; i < 8; i++) {
          int l = lane + (i << 6);
          if (l < Ln) mx = fmaxf(mx, ss[l]);
        }
        for (int o = 32; o; o >>= 1) mx = fmaxf(mx, __shfl_xor(mx, o));
        float sum = 0.f;
        for (int i = 0; i < 8; i++) {
          int l = lane + (i << 6);
          if (l < Ln) { float e = expf(ss[l] - mx); es[l] = e; sum += e; }
        }
        for (int o = 32; o; o >>= 1) sum += __shfl_xor(sum, o);
        if (lane == 0) misc[1] = 1.f / sum;
      }
      __syncthreads();
      {  // cu[u] = inv * sum_l es[l] * ul[l][u]
        const int u = tid & 127, lc = tid >> 7;
        const int lend = (lc * 64 + 64 < Ln) ? lc * 64 + 64 : Ln;
        float a = 0.f;
        if (mode) {
          const u16* q = (const u16*)ulat + ((size_t)blk * Ln) * UDn + u;
          for (int l = lc * 64; l < lend; l++) a = fmaf(es[l], b2f(q[l * UDn]), a);
        } else {
          const float* q = (const float*)ulat + ((size_t)blk * Ln) * UDn + u;
          for (int l = lc * 64; l < lend; l++) a = fmaf(es[l], q[l * UDn], a);
        }
        Bpart[lc * UDn + u] = a;
      }
      __syncthreads();
      if (tid < 128) {
        float s = 0.f;
#pragma unroll
        for (int c = 0; c < 8; c++) s += Bpart[c * UDn + tid];
        cuvws[blk * 128 + tid] = s * misc[1];
      }
      __syncthreads();
      if (tid == 0) { __threadfence(); arrive(flg + 1); }
    }

    // ---- cc = tanh(catWl.h + M2.cu + cbias), j-split across members -------
    // exact v2 order: half-k then half-u per accumulator (ascending nests),
    // halves combined as ccp[0]+ccp[1]+cb.
    if (wv == 0) waitGe(flg + 1, 16u);
    __syncthreads();
    if (tid < 512) {
      const int r = tid >> 5, jl = (tid >> 1) & 15, hf = tid & 1;
      const int bg = r * 8 + gt;
      const float* hp = hnw + bg * Hn;
      const float* cwb = cWT_l + jl * 516;
      const float* m2b = M2T_l + jl * 132;
      const float* cup = cuvws + bg * 128;
      float a = 0.f;
#pragma unroll 8
      for (int k4 = hf * 64; k4 < hf * 64 + 64; k4++) {
        const f4 w = *(const f4*)(cwb + k4 * 4);
        const f4 x = *(const f4*)(hp + k4 * 4);
        a = fmaf(w.w, x.w, fmaf(w.z, x.z, fmaf(w.y, x.y, fmaf(w.x, x.x, a))));
      }
#pragma unroll
      for (int u4 = hf * 16; u4 < hf * 16 + 16; u4++) {
        const f4 w = *(const f4*)(m2b + u4 * 4);
        const f4 x = *(const f4*)(cup + u4 * 4);
        a = fmaf(w.w, x.w, fmaf(w.z, x.z, fmaf(w.y, x.y, fmaf(w.x, x.x, a))));
      }
      ccp2[(r * 16 + jl) * 2 + hf] = a;
    }
    __syncthreads();
    if (tid < 256) {
      const int r = tid >> 4, jl = tid & 15;
      const int bg = r * 8 + gt;
      ccbF[bg * Hn + m * 16 + jl] =
          tanhf(ccp2[(r * 16 + jl) * 2] + ccp2[(r * 16 + jl) * 2 + 1] + cb_l[jl]);
    }
    __syncthreads();
    if (tid == 0) { __threadfence(); arrive(flg + 2); }

    // ---- logits + argmax + output (owners; verbatim v2) -------------------
    if (m < 16) {
      if (wv == 0) waitGe(flg + 2, 32u);
      __syncthreads();
      if (tid < Hn) ccs[tid] = ccbF[blk * Hn + tid];
      __syncthreads();
      if (lane < Vn) {
        const int j0 = wv << 5;
        float part = 0.f;
#pragma unroll
        for (int q = 0; q < 32; q++) part = fmaf(ccs[j0 + q], oWT[(j0 + q) * 34 + lane], part);
        lgs[wv * 34 + lane] = part;
      }
      __syncthreads();
      if (wv == 0) {
        float lg = -3.4e38f;
        int idx = 0;
        if (lane < Vn) {
          float s = obF[lane];
#pragma unroll
          for (int w2 = 0; w2 < 16; w2++) s += lgs[w2 * 34 + lane];
          if (mode) ((u16*)out)[(size_t)blk * (Vn * Ln) + lane * Ln + t] = f2b(s);
          else ((float*)out)[(size_t)blk * (Vn * Ln) + lane * Ln + t] = s;
          lg = s;
          idx = lane;
        }
        for (int o = 32; o; o >>= 1) {  // np argmax: first max wins
          const float ov = __shfl_down(lg, o);
          const int oi = __shfl_down(idx, o);
          if (ov > lg || (ov == lg && oi < idx)) { lg = ov; idx = oi; }
        }
        if (lane == 0) tokb[blk] = idx;
        __threadfence();
        if (lane == 0) arrive(flg + 3);
      }
    }
  }
}

extern "C" void kernel_launch(void* const* d_in, const int* in_sizes, int n_in,
                              void* d_out, int out_size, void* d_ws, size_t ws_size,
                              hipStream_t stream) {
  (void)in_sizes; (void)n_in; (void)out_size;
  if (ws_size < (size_t)W_END * 4) return;  // needs ~1.6 MB scratch
  hipLaunchKernelGGL(rnn_v3, dim3(NB), dim3(NT), 0, stream,
                     d_in[0],   // latent
                     d_in[1],   // upsampled_latent
                     d_in[3],   // embed (d_in[2]=target unused in eval)
                     d_in[4],   // hid_W
                     d_in[5],   // hid_b
                     d_in[6],   // mem_W
                     d_in[7],   // mem_b
                     d_in[8],   // W_ih
                     d_in[9],   // W_hh
                     d_in[10],  // b_ih
                     d_in[11],  // b_hh
                     d_in[12],  // cat_W
                     d_in[13],  // cat_b
                     d_in[14],  // out_W
                     d_in[15],  // out_b
                     d_out, (u32*)d_ws);
}

// Round 2
// 104296.375 us; speedup vs baseline: 1.3227x; 1.2889x over previous
//
#include <hip/hip_runtime.h>
#include <hip/hip_bf16.h>
#include <math.h>

// ============================================================================
// RNNDecoder v4: 128 fully independent persistent blocks (one batch row per
// block). Zero inter-block communication in the 500-step loop: h-state,
// token, and the row's ulat tile live in LDS; weights stream from the
// original input buffers (L2-resident per XCD, never invalidated since no
// agent-scope atomics run in the loop). Arithmetic orders replicate v2/v3
// exactly (same passing argmax trajectory). One cooperative init (GEM/M2/cb
// tables) + sentinel device barrier, then no global sync at all.
// ============================================================================

typedef unsigned short u16;
typedef unsigned int u32;
typedef float f4 __attribute__((ext_vector_type(4)));

#define NB 128
#define NT 1024
#define Ln 500
#define Hn 512
#define LDn 256
#define UDn 128
#define Vn 33
#define Tn 500
#define SENT_V 0x9E3779B1u

// ---- workspace u32 offsets ----
#define W_INITC 0u
#define W_SENT  1u
#define W_GEM   64u        // f32 [33][1536]   embed@W_ih^T + b_ih
#define W_M2    50752u     // f32 [512 j][128 u] catW_right@memW
#define W_CB    116288u    // f32 [512]        cat_b + catWr@mem_b
#define W_END   116800u    // ~467 KB

__device__ __forceinline__ float b2f(u16 v) {
  u32 x = ((u32)v) << 16; float f; __builtin_memcpy(&f, &x, 4); return f;
}
__device__ __forceinline__ float bitsf(u32 x) {
  float f; __builtin_memcpy(&f, &x, 4); return f;
}
__device__ __forceinline__ u16 f2b(float f) {  // RNE
  u32 x; __builtin_memcpy(&x, &f, 4);
  x += 0x7fffu + ((x >> 16) & 1u);
  return (u16)(x >> 16);
}
// mode==1: buffer holds bf16; mode==0: fp32
__device__ __forceinline__ float ldv(const void* p, size_t i, int mode) {
  return mode ? b2f(((const u16*)p)[i]) : ((const float*)p)[i];
}
__device__ __forceinline__ u32 aload(u32* p) {
  return __hip_atomic_load(p, __ATOMIC_ACQUIRE, __HIP_MEMORY_SCOPE_AGENT);
}
__device__ __forceinline__ void waitGe(u32* p, u32 tgt) {
  while (aload(p) < tgt) __builtin_amdgcn_s_sleep(4);
}
__device__ __forceinline__ void arrive(u32* p) {
  __hip_atomic_fetch_add(p, 1u, __ATOMIC_RELEASE, __HIP_MEMORY_SCOPE_AGENT);
}
__device__ __forceinline__ void astore(u32* p, u32 v) {
  __hip_atomic_store(p, v, __ATOMIC_RELEASE, __HIP_MEMORY_SCOPE_AGENT);
}

extern "C" __global__ void __launch_bounds__(1024)
rnn_v4(const void* latent, const void* ulat, const void* embd,
       const void* hidW, const void* hidb, const void* memW, const void* memb,
       const void* Wih, const void* Whh, const void* bih, const void* bhh,
       const void* catW, const void* catb, const void* outW, const void* outb,
       void* out, u32* ws) {
  // ---- LDS: per-row persistent state + phase-local arena ----
  __shared__ __align__(16) u16  ulat_l[Ln * 130];  // 130000 B (mode1 only)
  __shared__ __align__(16) float h_l[Hn];          // 2048 B, live 500 steps
  __shared__ __align__(16) char  arena[12288];     // phase-local scratch
  __shared__ float misc_l[2];                      // [0]=s0 [1]=inv_sum
  __shared__ int   s_tok;
  __shared__ u32   s_det;

  const int tid = threadIdx.x, blk = blockIdx.x;
  const int wv = tid >> 6, lane = tid & 63;
  const int gtid = blk * NT + tid;

  // ---- dtype detection: embed row PAD=1 is zero iff bf16 (verbatim) ----
  if (tid == 0) s_det = 0u;
  __syncthreads();
  if (tid < 256) {
    u32 v = ((const u32*)embd)[256 + tid];
    if (v) atomicOr(&s_det, 1u);
  }
  __syncthreads();
  const int mode = (s_det == 0u) ? 1 : 0;

  float* GEM = (float*)(ws + W_GEM);
  float* M2  = (float*)(ws + W_M2);
  float* cbF = (float*)(ws + W_CB);

  // ---- arena views (byte offsets; phases barrier-separated) ----
  float* ghq   = (float*)arena;            // GRU: [1536] dot+bhh      6144 B
  float* ps    = (float*)arena;            // attn: [128]              [0,512)
  float* ss    = (float*)(arena + 512);    // attn: [500]              [512,2512)
  float* es    = (float*)(arena + 2560);   // attn: [500]
  float* Bpart = (float*)(arena + 4608);   // attn: [8][128]           [4608,8704)
  float* cuv   = (float*)(arena + 8704);   // attn: [128]              [8704,9216)
  float* ccp2  = (float*)arena;            // cc:  [512][2]            [0,4096)
  float* ccs   = (float*)(arena + 4608);   // cc:  [512]               [4608,6656)
  float* lgs   = (float*)(arena + 6656);   // log: [16*34]             [6656,8832)

  // ======================= per-block private init ===========================
  if (mode) {  // row's ulat tile -> LDS (padded stride 130 for bank spread)
    const u16* src = (const u16*)ulat + (size_t)blk * Ln * UDn;
    for (int i = tid; i < Ln * UDn; i += NT) {
      int l = i >> 7, c = i & 127;
      ulat_l[l * 130 + c] = src[(size_t)l * UDn + c];
    }
  }
  if (tid < Hn) {  // h0 = latent @ hidW^T + hidb  (v3-exact order)
    int k = tid;
    float a = ldv(hidb, k, mode);
    for (int q = 0; q < LDn; q++)
      a += ldv(latent, (size_t)blk * LDn + q, mode) * ldv(hidW, (size_t)k * LDn + q, mode);
    h_l[k] = a;
  }
  if (tid == 0) s_tok = 0;  // SOS

  // ======================= cooperative ws table build =======================
  if (gtid < 50688) {                                  // GEM = embed@Wih^T+bih
    int v = gtid / 1536, j = gtid - v * 1536;
    float a = ldv(bih, j, mode);
    for (int k = 0; k < Hn; k++)
      a += ldv(embd, (size_t)v * Hn + k, mode) * ldv(Wih, (size_t)j * Hn + k, mode);
    GEM[gtid] = a;
  }
  if (gtid < 65536) {                                  // M2[j][u] = catWr@memW
    int j = gtid >> 7, u = gtid & 127;
    float a = 0.f;
    for (int h = 0; h < Hn; h++)
      a += ldv(catW, (size_t)j * 1024 + 512 + h, mode) * ldv(memW, (size_t)h * UDn + u, mode);
    M2[(size_t)j * 128 + u] = a;
  }
  if (gtid >= 65536 && gtid < 66048) {                 // cbias
    int j = gtid - 65536;
    float a = ldv(catb, j, mode);
    for (int h = 0; h < Hn; h++)
      a += ldv(catW, (size_t)j * 1024 + 512 + h, mode) * ldv(memb, h, mode);
    cbF[j] = a;
  }
  __threadfence();
  __syncthreads();
  if (tid == 0) {  // poison-agnostic device barrier (proven v2/v3 pattern)
    if (blk == 0) {
      __hip_atomic_store(ws + W_INITC, 0u, __ATOMIC_RELAXED, __HIP_MEMORY_SCOPE_AGENT);
      astore(ws + W_SENT, SENT_V);
    }
    while (aload(ws + W_SENT) != SENT_V) __builtin_amdgcn_s_sleep(8);
    arrive(ws + W_INITC);
    waitGe(ws + W_INITC, NB);
  }
  __syncthreads();

  // ======================= 500 decode steps (no global sync) ================
  for (int t = 0; t < Tn; t++) {
    __syncthreads();  // s_tok + prev-step arena reads complete

    // ---- GRU dots: 1536 full-k rows, exact v2 8-chunk f4-nest order -------
    // thread t handles row d=t (all) and d=t+1024 (t<512): 16 waves busy.
    for (int rep = 0; rep < 2; rep++) {
      const int d = tid + rep * 1024;
      if (d >= 1536) break;  // wave-uniform (tid<512)
      float s = 0.f;
      if (mode) {
        const u32* wr = (const u32*)((const u16*)Whh + (size_t)d * 512);
        for (int c = 0; c < 8; c++) {
          float a = 0.f;
          const u32* wc = wr + c * 32;
#pragma unroll
          for (int k4 = 0; k4 < 16; k4++) {
            const u32 d0 = wc[k4 * 2], d1 = wc[k4 * 2 + 1];
            const float w0 = bitsf(d0 << 16), w1 = bitsf(d0 & 0xffff0000u);
            const float w2 = bitsf(d1 << 16), w3 = bitsf(d1 & 0xffff0000u);
            const f4 x = *(const f4*)(h_l + c * 64 + k4 * 4);
            a = fmaf(w0, x.x, fmaf(w1, x.y, fmaf(w2, x.z, fmaf(w3, x.w, a))));
          }
          s += a;
        }
      } else {
        const float* wr = (const float*)Whh + (size_t)d * 512;
        for (int c = 0; c < 8; c++) {
          float a = 0.f;
#pragma unroll
          for (int k4 = 0; k4 < 16; k4++) {
            const f4 w = *(const f4*)(wr + c * 64 + k4 * 4);
            const f4 x = *(const f4*)(h_l + c * 64 + k4 * 4);
            a = fmaf(w.x, x.x, fmaf(w.y, x.y, fmaf(w.z, x.z, fmaf(w.w, x.w, a))));
          }
          s += a;
        }
      }
      ghq[d] = s + ldv(bhh, d, mode);
    }
    __syncthreads();

    // ---- gate nonlinearity + h update (verbatim v2 formulas) --------------
    float hnew = 0.f;
    if (tid < Hn) {
      const int j = tid;
      int tk = s_tok;
      if ((unsigned)tk > 32u) tk = 0;  // defensive clamp
      const float giR = GEM[tk * 1536 + j];
      const float giZ = GEM[tk * 1536 + 512 + j];
      const float giN = GEM[tk * 1536 + 1024 + j];
      const float rr = 1.f / (1.f + expf(-(giR + ghq[j])));
      const float zz = 1.f / (1.f + expf(-(giZ + ghq[512 + j])));
      const float nn = tanhf(giN + rr * ghq[1024 + j]);
      const float hv = h_l[j];
      hnew = (1.f - zz) * nn + zz * hv;
    }
    __syncthreads();
    if (tid < Hn) h_l[tid] = hnew;
    __syncthreads();

    // ---- attention: p = memW^T h_new (verbatim v2) ------------------------
    {
      const int u = tid & 127, c8 = tid >> 7;
      float a = 0.f;
      for (int k = c8 * 64; k < c8 * 64 + 64; k++)
        a = fmaf(ldv(memW, (size_t)k * UDn + u, mode), h_l[k], a);
      Bpart[c8 * UDn + u] = a;
    }
    __syncthreads();
    if (tid < 128) {
      float s = 0.f;
#pragma unroll
      for (int c = 0; c < 8; c++) s += Bpart[c * UDn + tid];
      ps[tid] = s;
    } else if (tid < 192) {  // s0 = h_new . mem_b
      const int ln = tid - 128;
      float a = 0.f;
#pragma unroll
      for (int i = 0; i < 8; i++) { int k = ln + i * 64; a = fmaf(h_l[k], ldv(memb, k, mode), a); }
      for (int o = 32; o; o >>= 1) a += __shfl_down(a, o);
      if (ln == 0) misc_l[0] = a;
    }
    __syncthreads();

    // ---- scores[l] = p . ul[l] + s0 (same math; ulat from LDS in mode1) ---
    {
      const int l = (wv << 5) + (lane >> 1), uh = lane & 1;
      float val = 0.f;
      if (l < Ln) {
        if (mode) {
          const u32* q = (const u32*)ulat_l + l * 65 + uh * 32;
          for (int i = 0; i < 32; i++) {
            const u32 d = q[i];
            val = fmaf(bitsf(d << 16), ps[uh * 64 + i * 2], val);
            val = fmaf(bitsf(d & 0xffff0000u), ps[uh * 64 + i * 2 + 1], val);
          }
        } else {
          const float* q = (const float*)ulat + ((size_t)blk * Ln + l) * UDn + uh * 64;
          for (int i = 0; i < 64; i++) val = fmaf(q[i], ps[uh * 64 + i], val);
        }
      }
      const float v2v = __shfl_down(val, 1);
      if ((lane & 1) == 0 && l < Ln) ss[l] = val + v2v + misc_l[0];
    }
    __syncthreads();
    if (wv == 0) {  // softmax stats over 500 (verbatim)
      float mx = -3.4e38f;
      for (int i = 0; i < 8; i++) {
        int l = lane + (i << 6);
        if (l < Ln) mx = fmaxf(mx, ss[l]);
      }
      for (int o = 32; o; o >>= 1) mx = fmaxf(mx, __shfl_xor(mx, o));
      float sum = 0.f;
      for (int i = 0; i < 8; i++) {
        int l = lane + (i << 6);
        if (l < Ln) { float e = expf(ss[l] - mx); es[l] = e; sum += e; }
      }
      for (int o = 32; o; o >>= 1) sum += __shfl_xor(sum, o);
      if (lane == 0) misc_l[1] = 1.f / sum;
    }
    __syncthreads();

    // ---- cu[u] = inv * sum_l es[l] * ul[l][u] (verbatim math) -------------
    {
      const int u = tid & 127, lc = tid >> 7;
      const int lend = (lc * 64 + 64 < Ln) ? lc * 64 + 64 : Ln;
      float a = 0.f;
      if (mode) {
        for (int l = lc * 64; l < lend; l++) a = fmaf(es[l], b2f(ulat_l[l * 130 + u]), a);
      } else {
        const float* q = (const float*)ulat + ((size_t)blk * Ln) * UDn + u;
        for (int l = lc * 64; l < lend; l++) a = fmaf(es[l], q[(size_t)l * UDn], a);
      }
      Bpart[lc * UDn + u] = a;
    }
    __syncthreads();
    if (tid < 128) {
      float s = 0.f;
#pragma unroll
      for (int c = 0; c < 8; c++) s += Bpart[c * UDn + tid];
      cuv[tid] = s * misc_l[1];
    }
    __syncthreads();

    // ---- cc = tanh(catWl.h + M2.cu + cbias) (verbatim v2 order) -----------
    {
      const int j = tid & 511, hf = tid >> 9;
      float a = 0.f;
      if (mode) {
        const u32* cw = (const u32*)((const u16*)catW + (size_t)j * 1024) + hf * 128;
        for (int k2 = 0; k2 < 128; k2++) {
          const u32 d = cw[k2];
          a = fmaf(bitsf(d << 16), h_l[hf * 256 + k2 * 2], a);
          a = fmaf(bitsf(d & 0xffff0000u), h_l[hf * 256 + k2 * 2 + 1], a);
        }
      } else {
        const float* cw = (const float*)catW + (size_t)j * 1024;
        for (int k = hf * 256; k < hf * 256 + 256; k++)
          a = fmaf(cw[k], h_l[k], a);
      }
      const float* m2r = M2 + (size_t)j * 128;
      for (int u = hf * 64; u < hf * 64 + 64; u++)
        a = fmaf(m2r[u], cuv[u], a);
      ccp2[j * 2 + hf] = a;
    }
    __syncthreads();
    if (tid < Hn)
      ccs[tid] = tanhf(ccp2[tid * 2] + ccp2[tid * 2 + 1] + cbF[tid]);
    __syncthreads();

    // ---- logits + argmax + output (verbatim v2; outW read = oWT values) ---
    if (lane < Vn) {
      const int j0 = wv << 5;
      float part = 0.f;
#pragma unroll
      for (int q = 0; q < 32; q++)
        part = fmaf(ccs[j0 + q], ldv(outW, (size_t)lane * Hn + j0 + q, mode), part);
      lgs[wv * 34 + lane] = part;
    }
    __syncthreads();
    if (wv == 0) {
      float lg = -3.4e38f;
      int idx = 0;
      if (lane < Vn) {
        float s = (lane < Vn) ? ldv(outb, lane, mode) : 0.f;
#pragma unroll
        for (int w2 = 0; w2 < 16; w2++) s += lgs[w2 * 34 + lane];
        if (mode) ((u16*)out)[(size_t)blk * (Vn * Ln) + lane * Ln + t] = f2b(s);
        else ((float*)out)[(size_t)blk * (Vn * Ln) + lane * Ln + t] = s;
        lg = s;
        idx = lane;
      }
      for (int o = 32; o; o >>= 1) {  // np argmax: first max wins
        const float ov = __shfl_down(lg, o);
        const int oi = __shfl_down(idx, o);
        if (ov > lg || (ov == lg && oi < idx)) { lg = ov; idx = oi; }
      }
      if (lane == 0) s_tok = idx;
    }
  }
}

extern "C" void kernel_launch(void* const* d_in, const int* in_sizes, int n_in,
                              void* d_out, int out_size, void* d_ws, size_t ws_size,
                              hipStream_t stream) {
  (void)in_sizes; (void)n_in; (void)out_size;
  if (ws_size < (size_t)W_END * 4) return;  // needs ~0.5 MB scratch
  hipLaunchKernelGGL(rnn_v4, dim3(NB), dim3(NT), 0, stream,
                     d_in[0],   // latent
                     d_in[1],   // upsampled_latent
                     d_in[3],   // embed (d_in[2]=target unused in eval)
                     d_in[4],   // hid_W
                     d_in[5],   // hid_b
                     d_in[6],   // mem_W
                     d_in[7],   // mem_b
                     d_in[8],   // W_ih
                     d_in[9],   // W_hh
                     d_in[10],  // b_ih
                     d_in[11],  // b_hh
                     d_in[12],  // cat_W
                     d_in[13],  // cat_b
                     d_in[14],  // out_W
                     d_in[15],  // out_b
                     d_out, (u32*)d_ws);
}

// Round 3
// 91546.301 us; speedup vs baseline: 1.5069x; 1.1393x over previous
//
#include <hip/hip_runtime.h>
#include <hip/hip_bf16.h>
#include <math.h>

// ============================================================================
// RNNDecoder v5: v4 structure (128 independent persistent blocks, one row
// each, zero inter-block sync in the loop) with latency-shaped inner loops:
// all weight streams are batched dwordx4 loads with one wait per batch, GRU
// h-slice lives in registers (no LDS in the global-load inner loop), cc/p/cu
// loads batched/unrolled. Every accumulation chain is element-for-element
// identical to v4's (same passing argmax trajectory).
// ============================================================================

typedef unsigned short u16;
typedef unsigned int u32;
typedef float f4 __attribute__((ext_vector_type(4)));
typedef u32 u4 __attribute__((ext_vector_type(4)));

#define NB 128
#define NT 1024
#define Ln 500
#define Hn 512
#define LDn 256
#define UDn 128
#define Vn 33
#define Tn 500
#define SENT_V 0x9E3779B1u

// ---- workspace u32 offsets ----
#define W_INITC 0u
#define W_SENT  1u
#define W_GEM   64u        // f32 [33][1536]   embed@W_ih^T + b_ih
#define W_M2    50752u     // f32 [512 j][128 u] catW_right@memW
#define W_CB    116288u    // f32 [512]        cat_b + catWr@mem_b
#define W_END   116800u    // ~467 KB

__device__ __forceinline__ float b2f(u16 v) {
  u32 x = ((u32)v) << 16; float f; __builtin_memcpy(&f, &x, 4); return f;
}
__device__ __forceinline__ float bitsf(u32 x) {
  float f; __builtin_memcpy(&f, &x, 4); return f;
}
#define LO16(d) bitsf((u32)(d) << 16)
#define HI16(d) bitsf((u32)(d) & 0xffff0000u)
__device__ __forceinline__ u16 f2b(float f) {  // RNE
  u32 x; __builtin_memcpy(&x, &f, 4);
  x += 0x7fffu + ((x >> 16) & 1u);
  return (u16)(x >> 16);
}
// mode==1: buffer holds bf16; mode==0: fp32
__device__ __forceinline__ float ldv(const void* p, size_t i, int mode) {
  return mode ? b2f(((const u16*)p)[i]) : ((const float*)p)[i];
}
__device__ __forceinline__ u32 aload(u32* p) {
  return __hip_atomic_load(p, __ATOMIC_ACQUIRE, __HIP_MEMORY_SCOPE_AGENT);
}
__device__ __forceinline__ void waitGe(u32* p, u32 tgt) {
  while (aload(p) < tgt) __builtin_amdgcn_s_sleep(4);
}
__device__ __forceinline__ void arrive(u32* p) {
  __hip_atomic_fetch_add(p, 1u, __ATOMIC_RELEASE, __HIP_MEMORY_SCOPE_AGENT);
}
__device__ __forceinline__ void astore(u32* p, u32 v) {
  __hip_atomic_store(p, v, __ATOMIC_RELEASE, __HIP_MEMORY_SCOPE_AGENT);
}

extern "C" __global__ void __launch_bounds__(1024)
rnn_v5(const void* latent, const void* ulat, const void* embd,
       const void* hidW, const void* hidb, const void* memW, const void* memb,
       const void* Wih, const void* Whh, const void* bih, const void* bhh,
       const void* catW, const void* catb, const void* outW, const void* outb,
       void* out, u32* ws) {
  // ---- LDS: per-row persistent state + phase-local arena ----
  __shared__ __align__(16) u16  ulat_l[Ln * 130];  // 130000 B (mode1 only)
  __shared__ __align__(16) float h_l[Hn];          // 2048 B, live 500 steps
  __shared__ __align__(16) char  arena[12288];     // phase-local scratch
  __shared__ __align__(16) float bhh_l[1536];      // 6144 B
  __shared__ float misc_l[2];                      // [0]=s0 [1]=inv_sum
  __shared__ int   s_tok;
  __shared__ u32   s_det;

  const int tid = threadIdx.x, blk = blockIdx.x;
  const int wv = tid >> 6, lane = tid & 63;
  const int gtid = blk * NT + tid;

  // ---- dtype detection: embed row PAD=1 is zero iff bf16 (verbatim) ----
  if (tid == 0) s_det = 0u;
  __syncthreads();
  if (tid < 256) {
    u32 v = ((const u32*)embd)[256 + tid];
    if (v) atomicOr(&s_det, 1u);
  }
  __syncthreads();
  const int mode = (s_det == 0u) ? 1 : 0;

  float* GEM = (float*)(ws + W_GEM);
  float* M2  = (float*)(ws + W_M2);
  float* cbF = (float*)(ws + W_CB);

  // ---- arena views (byte offsets; phases barrier-separated) ----
  float* ghq   = (float*)arena;            // GRU: [1536] dot+bhh      6144 B
  float* ps    = (float*)arena;            // attn: [128]              [0,512)
  float* ss    = (float*)(arena + 512);    // attn: [500]              [512,2512)
  float* es    = (float*)(arena + 2560);   // attn: [500]
  float* Bpart = (float*)(arena + 4608);   // attn: [8][128]           [4608,8704)
  float* cuv   = (float*)(arena + 8704);   // attn: [128]              [8704,9216)
  float* ccp2  = (float*)arena;            // cc:  [512][2]            [0,4096)
  float* ccs   = (float*)(arena + 4608);   // cc:  [512]               [4608,6656)
  float* lgs   = (float*)(arena + 6656);   // log: [16*34]             [6656,8832)

  // ======================= per-block private init ===========================
  if (mode) {  // row's ulat tile -> LDS (padded stride 130 for bank spread)
    const u16* src = (const u16*)ulat + (size_t)blk * Ln * UDn;
    for (int i = tid; i < Ln * UDn; i += NT) {
      int l = i >> 7, c = i & 127;
      ulat_l[l * 130 + c] = src[(size_t)l * UDn + c];
    }
  }
  for (int i = tid; i < 1536; i += NT) bhh_l[i] = ldv(bhh, i, mode);
  if (tid < Hn) {  // h0 = latent @ hidW^T + hidb  (v4-exact order)
    int k = tid;
    float a = ldv(hidb, k, mode);
    for (int q = 0; q < LDn; q++)
      a += ldv(latent, (size_t)blk * LDn + q, mode) * ldv(hidW, (size_t)k * LDn + q, mode);
    h_l[k] = a;
  }
  if (tid == 0) s_tok = 0;  // SOS

  // ======================= cooperative ws table build =======================
  if (gtid < 50688) {                                  // GEM = embed@Wih^T+bih
    int v = gtid / 1536, j = gtid - v * 1536;
    float a = ldv(bih, j, mode);
    for (int k = 0; k < Hn; k++)
      a += ldv(embd, (size_t)v * Hn + k, mode) * ldv(Wih, (size_t)j * Hn + k, mode);
    GEM[gtid] = a;
  }
  if (gtid < 65536) {                                  // M2[j][u] = catWr@memW
    int j = gtid >> 7, u = gtid & 127;
    float a = 0.f;
    for (int h = 0; h < Hn; h++)
      a += ldv(catW, (size_t)j * 1024 + 512 + h, mode) * ldv(memW, (size_t)h * UDn + u, mode);
    M2[(size_t)j * 128 + u] = a;
  }
  if (gtid >= 65536 && gtid < 66048) {                 // cbias
    int j = gtid - 65536;
    float a = ldv(catb, j, mode);
    for (int h = 0; h < Hn; h++)
      a += ldv(catW, (size_t)j * 1024 + 512 + h, mode) * ldv(memb, h, mode);
    cbF[j] = a;
  }
  __threadfence();
  __syncthreads();
  if (tid == 0) {  // poison-agnostic device barrier (proven pattern)
    if (blk == 0) {
      __hip_atomic_store(ws + W_INITC, 0u, __ATOMIC_RELAXED, __HIP_MEMORY_SCOPE_AGENT);
      astore(ws + W_SENT, SENT_V);
    }
    while (aload(ws + W_SENT) != SENT_V) __builtin_amdgcn_s_sleep(8);
    arrive(ws + W_INITC);
    waitGe(ws + W_INITC, NB);
  }
  __syncthreads();

  // ======================= 500 decode steps (no global sync) ================
  for (int t = 0; t < Tn; t++) {
    __syncthreads();  // s_tok + prev-step arena reads complete

    // ---- GRU dots: lane (r,c) = (row-in-group, chunk). Each lane computes
    // v4's exact chunk-c accumulation (descending fma nest, k4 ascending);
    // chunk partials folded strictly left-to-right via shfl (== v4's s+=a_c).
    {
      const int r = lane >> 3, c = lane & 7;
      f4 xv[16];  // this lane's h slice: chunk c = h[c*64 .. c*64+64)
#pragma unroll
      for (int i = 0; i < 16; i++) xv[i] = *(const f4*)(h_l + c * 64 + i * 4);
      const int base = lane & 56;
      if (mode) {
        for (int g = 0; g < 12; g++) {
          const int d = wv * 96 + g * 8 + r;
          const u4* wp = (const u4*)Whh + (size_t)d * 64 + c * 8;
          float a = 0.f;
#pragma unroll
          for (int b = 0; b < 2; b++) {
            u4 q[4];
#pragma unroll
            for (int s2 = 0; s2 < 4; s2++) q[s2] = wp[b * 4 + s2];
#pragma unroll
            for (int s2 = 0; s2 < 4; s2++) {
              const f4 xa = xv[b * 8 + s2 * 2], xb = xv[b * 8 + s2 * 2 + 1];
              a = fmaf(LO16(q[s2].x), xa.x, fmaf(HI16(q[s2].x), xa.y,
                  fmaf(LO16(q[s2].y), xa.z, fmaf(HI16(q[s2].y), xa.w, a))));
              a = fmaf(LO16(q[s2].z), xb.x, fmaf(HI16(q[s2].z), xb.y,
                  fmaf(LO16(q[s2].w), xb.z, fmaf(HI16(q[s2].w), xb.w, a))));
            }
          }
          float s = __shfl(a, base);
#pragma unroll
          for (int c2 = 1; c2 < 8; c2++) s += __shfl(a, base + c2);
          if (c == 0) ghq[d] = s + bhh_l[d];
        }
      } else {
        for (int g = 0; g < 12; g++) {
          const int d = wv * 96 + g * 8 + r;
          const f4* wp = (const f4*)Whh + (size_t)d * 128 + c * 16;
          float a = 0.f;
#pragma unroll
          for (int b = 0; b < 4; b++) {
            f4 q[4];
#pragma unroll
            for (int s2 = 0; s2 < 4; s2++) q[s2] = wp[b * 4 + s2];
#pragma unroll
            for (int s2 = 0; s2 < 4; s2++) {
              const f4 xa = xv[b * 4 + s2];
              a = fmaf(q[s2].x, xa.x, fmaf(q[s2].y, xa.y,
                  fmaf(q[s2].z, xa.z, fmaf(q[s2].w, xa.w, a))));
            }
          }
          float s = __shfl(a, base);
#pragma unroll
          for (int c2 = 1; c2 < 8; c2++) s += __shfl(a, base + c2);
          if (c == 0) ghq[d] = s + bhh_l[d];
        }
      }
    }
    __syncthreads();

    // ---- gate nonlinearity + h update (verbatim v4 formulas) --------------
    float hnew = 0.f;
    if (tid < Hn) {
      const int j = tid;
      int tk = s_tok;
      if ((unsigned)tk > 32u) tk = 0;  // defensive clamp
      const float giR = GEM[tk * 1536 + j];
      const float giZ = GEM[tk * 1536 + 512 + j];
      const float giN = GEM[tk * 1536 + 1024 + j];
      const float rr = 1.f / (1.f + expf(-(giR + ghq[j])));
      const float zz = 1.f / (1.f + expf(-(giZ + ghq[512 + j])));
      const float nn = tanhf(giN + rr * ghq[1024 + j]);
      const float hv = h_l[j];
      hnew = (1.f - zz) * nn + zz * hv;
    }
    __syncthreads();
    if (tid < Hn) h_l[tid] = hnew;
    __syncthreads();

    // ---- attention: p = memW^T h_new (v4 order; batched via unroll) -------
    {
      const int u = tid & 127, c8 = tid >> 7;
      float a = 0.f;
      if (mode) {
        const u16* mw = (const u16*)memW + u;
#pragma unroll 8
        for (int k = c8 * 64; k < c8 * 64 + 64; k++)
          a = fmaf(b2f(mw[(size_t)k * UDn]), h_l[k], a);
      } else {
        const float* mw = (const float*)memW + u;
#pragma unroll 8
        for (int k = c8 * 64; k < c8 * 64 + 64; k++)
          a = fmaf(mw[(size_t)k * UDn], h_l[k], a);
      }
      Bpart[c8 * UDn + u] = a;
    }
    __syncthreads();
    if (tid < 128) {
      float s = 0.f;
#pragma unroll
      for (int c = 0; c < 8; c++) s += Bpart[c * UDn + tid];
      ps[tid] = s;
    } else if (tid < 192) {  // s0 = h_new . mem_b
      const int ln = tid - 128;
      float a = 0.f;
#pragma unroll
      for (int i = 0; i < 8; i++) { int k = ln + i * 64; a = fmaf(h_l[k], ldv(memb, k, mode), a); }
      for (int o = 32; o; o >>= 1) a += __shfl_down(a, o);
      if (ln == 0) misc_l[0] = a;
    }
    __syncthreads();

    // ---- scores[l] = p . ul[l] + s0 (verbatim v4) -------------------------
    {
      const int l = (wv << 5) + (lane >> 1), uh = lane & 1;
      float val = 0.f;
      if (l < Ln) {
        if (mode) {
          const u32* q = (const u32*)ulat_l + l * 65 + uh * 32;
          for (int i = 0; i < 32; i++) {
            const u32 d = q[i];
            val = fmaf(bitsf(d << 16), ps[uh * 64 + i * 2], val);
            val = fmaf(bitsf(d & 0xffff0000u), ps[uh * 64 + i * 2 + 1], val);
          }
        } else {
          const float* q = (const float*)ulat + ((size_t)blk * Ln + l) * UDn + uh * 64;
          for (int i = 0; i < 64; i++) val = fmaf(q[i], ps[uh * 64 + i], val);
        }
      }
      const float v2v = __shfl_down(val, 1);
      if ((lane & 1) == 0 && l < Ln) ss[l] = val + v2v + misc_l[0];
    }
    __syncthreads();
    if (wv == 0) {  // softmax stats over 500 (verbatim)
      float mx = -3.4e38f;
      for (int i = 0; i < 8; i++) {
        int l = lane + (i << 6);
        if (l < Ln) mx = fmaxf(mx, ss[l]);
      }
      for (int o = 32; o; o >>= 1) mx = fmaxf(mx, __shfl_xor(mx, o));
      float sum = 0.f;
      for (int i = 0; i < 8; i++) {
        int l = lane + (i << 6);
        if (l < Ln) { float e = expf(ss[l] - mx); es[l] = e; sum += e; }
      }
      for (int o = 32; o; o >>= 1) sum += __shfl_xor(sum, o);
      if (lane == 0) misc_l[1] = 1.f / sum;
    }
    __syncthreads();

    // ---- cu[u] = inv * sum_l es[l] * ul[l][u] (v4 order, unroll-batched) --
    {
      const int u = tid & 127, lc = tid >> 7;
      const int lend = (lc * 64 + 64 < Ln) ? lc * 64 + 64 : Ln;
      float a = 0.f;
      if (mode) {
#pragma unroll 8
        for (int l = lc * 64; l < lend; l++) a = fmaf(es[l], b2f(ulat_l[l * 130 + u]), a);
      } else {
        const float* q = (const float*)ulat + ((size_t)blk * Ln) * UDn + u;
#pragma unroll 8
        for (int l = lc * 64; l < lend; l++) a = fmaf(es[l], q[(size_t)l * UDn], a);
      }
      Bpart[lc * UDn + u] = a;
    }
    __syncthreads();
    if (tid < 128) {
      float s = 0.f;
#pragma unroll
      for (int c = 0; c < 8; c++) s += Bpart[c * UDn + tid];
      cuv[tid] = s * misc_l[1];
    }
    __syncthreads();

    // ---- cc = tanh(catWl.h + M2.cu + cbias) (v4-exact chain, batched) -----
    {
      const int j = tid & 511, hf = tid >> 9;
      float a = 0.f;
      if (mode) {
        const u4* cw = (const u4*)((const u16*)catW + (size_t)j * 1024) + hf * 32;
#pragma unroll
        for (int b2 = 0; b2 < 4; b2++) {
          u4 q[8];
#pragma unroll
          for (int s2 = 0; s2 < 8; s2++) q[s2] = cw[b2 * 8 + s2];
#pragma unroll
          for (int s2 = 0; s2 < 8; s2++) {
            const int e = hf * 256 + b2 * 64 + s2 * 8;
            const f4 xa = *(const f4*)(h_l + e), xb = *(const f4*)(h_l + e + 4);
            a = fmaf(LO16(q[s2].x), xa.x, a); a = fmaf(HI16(q[s2].x), xa.y, a);
            a = fmaf(LO16(q[s2].y), xa.z, a); a = fmaf(HI16(q[s2].y), xa.w, a);
            a = fmaf(LO16(q[s2].z), xb.x, a); a = fmaf(HI16(q[s2].z), xb.y, a);
            a = fmaf(LO16(q[s2].w), xb.z, a); a = fmaf(HI16(q[s2].w), xb.w, a);
          }
        }
      } else {
        const f4* cw4 = (const f4*)catW + (size_t)j * 256 + hf * 64;
#pragma unroll
        for (int b2 = 0; b2 < 8; b2++) {
          f4 q[8];
#pragma unroll
          for (int s2 = 0; s2 < 8; s2++) q[s2] = cw4[b2 * 8 + s2];
#pragma unroll
          for (int s2 = 0; s2 < 8; s2++) {
            const int e = hf * 256 + b2 * 32 + s2 * 4;
            const f4 xa = *(const f4*)(h_l + e);
            a = fmaf(q[s2].x, xa.x, a); a = fmaf(q[s2].y, xa.y, a);
            a = fmaf(q[s2].z, xa.z, a); a = fmaf(q[s2].w, xa.w, a);
          }
        }
      }
      {  // M2 part (f32, ascending — v4-exact)
        const f4* m2 = (const f4*)(M2 + (size_t)j * 128) + hf * 16;
#pragma unroll
        for (int b2 = 0; b2 < 2; b2++) {
          f4 q[8];
#pragma unroll
          for (int s2 = 0; s2 < 8; s2++) q[s2] = m2[b2 * 8 + s2];
#pragma unroll
          for (int s2 = 0; s2 < 8; s2++) {
            const int e = hf * 64 + b2 * 32 + s2 * 4;
            const f4 xc = *(const f4*)(cuv + e);
            a = fmaf(q[s2].x, xc.x, a); a = fmaf(q[s2].y, xc.y, a);
            a = fmaf(q[s2].z, xc.z, a); a = fmaf(q[s2].w, xc.w, a);
          }
        }
      }
      ccp2[j * 2 + hf] = a;
    }
    __syncthreads();
    if (tid < Hn)
      ccs[tid] = tanhf(ccp2[tid * 2] + ccp2[tid * 2 + 1] + cbF[tid]);
    __syncthreads();

    // ---- logits + argmax + output (verbatim v4) ---------------------------
    if (lane < Vn) {
      const int j0 = wv << 5;
      float part = 0.f;
#pragma unroll
      for (int q = 0; q < 32; q++)
        part = fmaf(ccs[j0 + q], ldv(outW, (size_t)lane * Hn + j0 + q, mode), part);
      lgs[wv * 34 + lane] = part;
    }
    __syncthreads();
    if (wv == 0) {
      float lg = -3.4e38f;
      int idx = 0;
      if (lane < Vn) {
        float s = (lane < Vn) ? ldv(outb, lane, mode) : 0.f;
#pragma unroll
        for (int w2 = 0; w2 < 16; w2++) s += lgs[w2 * 34 + lane];
        if (mode) ((u16*)out)[(size_t)blk * (Vn * Ln) + lane * Ln + t] = f2b(s);
        else ((float*)out)[(size_t)blk * (Vn * Ln) + lane * Ln + t] = s;
        lg = s;
        idx = lane;
      }
      for (int o = 32; o; o >>= 1) {  // np argmax: first max wins
        const float ov = __shfl_down(lg, o);
        const int oi = __shfl_down(idx, o);
        if (ov > lg || (ov == lg && oi < idx)) { lg = ov; idx = oi; }
      }
      if (lane == 0) s_tok = idx;
    }
  }
}

extern "C" void kernel_launch(void* const* d_in, const int* in_sizes, int n_in,
                              void* d_out, int out_size, void* d_ws, size_t ws_size,
                              hipStream_t stream) {
  (void)in_sizes; (void)n_in; (void)out_size;
  if (ws_size < (size_t)W_END * 4) return;  // needs ~0.5 MB scratch
  hipLaunchKernelGGL(rnn_v5, dim3(NB), dim3(NT), 0, stream,
                     d_in[0],   // latent
                     d_in[1],   // upsampled_latent
                     d_in[3],   // embed (d_in[2]=target unused in eval)
                     d_in[4],   // hid_W
                     d_in[5],   // hid_b
                     d_in[6],   // mem_W
                     d_in[7],   // mem_b
                     d_in[8],   // W_ih
                     d_in[9],   // W_hh
                     d_in[10],  // b_ih
                     d_in[11],  // b_hh
                     d_in[12],  // cat_W
                     d_in[13],  // cat_b
                     d_in[14],  // out_W
                     d_in[15],  // out_b
                     d_out, (u32*)d_ws);
}